// Round 1
// baseline (825.310 us; speedup 1.0000x reference)
//
#include <hip/hip_runtime.h>

namespace {
constexpr int BATCH = 32, NWAY = 5, KSHOT = 5, NQ = 75, CH = 640, HW = 25;
constexpr int MS = NWAY * HW;   // 125
constexpr int CHW = CH * HW;    // 16000
constexpr float GAMMA = 20.f, GAMMA2 = 10.f;
constexpr double KATZ = 0.999;
constexpr float EPS = 1e-12f;
}

// Shot-mean + L2-normalize (over c) + transpose to sup_t[b][nk][c].
__global__ __launch_bounds__(256)
void prep_sup_kernel(const float* __restrict__ sup, float* __restrict__ sup_t) {
  __shared__ __align__(16) float m[CHW];   // mean tile [c][k]
  __shared__ float inv[HW];
  const int bn = blockIdx.x;               // b*NWAY + n
  const float* base = sup + (size_t)(bn / NWAY) * (KSHOT * NWAY * CHW)
                          + (size_t)(bn % NWAY) * (KSHOT * CHW);
  for (int idx = threadIdx.x; idx < CHW; idx += 256) {
    float s = 0.f;
    #pragma unroll
    for (int sh = 0; sh < KSHOT; ++sh) s += base[sh * CHW + idx];
    m[idx] = s * (1.f / KSHOT);
  }
  __syncthreads();
  {
    int i = threadIdx.x >> 3, s8 = threadIdx.x & 7;
    if (i < HW) {
      float p = 0.f;
      for (int c = s8; c < CH; c += 8) { float v = m[c * HW + i]; p += v * v; }
      p += __shfl_xor(p, 1); p += __shfl_xor(p, 2); p += __shfl_xor(p, 4);
      if (s8 == 0) inv[i] = rsqrtf(p + EPS);
    }
  }
  __syncthreads();
  float* outp = sup_t + (size_t)bn * CHW;  // [k][c], coalesced writes
  for (int idx = threadIdx.x; idx < CHW; idx += 256) {
    int k = idx / CH, c = idx - k * CH;
    outp[idx] = m[c * HW + k] * inv[k];
  }
}

// Per-(b,q): S GEMM -> softmaxes -> reduced 25x25 Katz solve -> outputs.
__global__ __launch_bounds__(256)
void melmask_kernel(const float* __restrict__ qry, const float* __restrict__ sup_t,
                    float* __restrict__ out) {
  __shared__ __align__(16) float smem[21760];
  float* qld   = smem;           // 16000: qry tile [c][i]; later reused for P/Q/solve
  float* Sld   = smem + 16000;   // 3125 (+pad): S[i][nk]
  float* stile = smem + 19136;   // 128x20 sup chunk
  float* invq  = smem + 21696;   // 25
  float* kqs   = smem + 21728;   // 25

  const int tid = threadIdx.x;
  const int bq = blockIdx.x;               // b*NQ + q
  const int b = bq / NQ;
  const float* qbase = qry + (size_t)bq * CHW;
  const float* sbase = sup_t + (size_t)b * (MS * CH);

  // stage qry tile (flat layout [c][i] identical to global)
  for (int idx = tid; idx < CHW / 4; idx += 256)
    ((float4*)qld)[idx] = ((const float4*)qbase)[idx];
  __syncthreads();

  // inverse L2 norms per query spatial position i
  {
    int i = tid >> 3, s8 = tid & 7;
    if (i < HW) {
      float p = 0.f;
      for (int c = s8; c < CH; c += 8) { float v = qld[c * HW + i]; p += v * v; }
      p += __shfl_xor(p, 1); p += __shfl_xor(p, 2); p += __shfl_xor(p, 4);
      if (s8 == 0) invq[i] = rsqrtf(p + EPS);
    }
  }

  // GEMM: S[i][nk] = sum_c qld[c*25+i] * sup_t[nk*640+c]   (25 x 125, K=640)
  const int ty = tid >> 4, tx = tid & 15;  // rows {ty, ty+16}, cols {tx+16j}
  float acc0[8], acc1[8];
  #pragma unroll
  for (int j = 0; j < 8; ++j) { acc0[j] = 0.f; acc1[j] = 0.f; }

  for (int c0 = 0; c0 < CH; c0 += 16) {
    __syncthreads();  // protect stile from previous iteration readers
    #pragma unroll
    for (int p = 0; p < 2; ++p) {
      int idx = p * 256 + tid;             // 0..511
      int nk = idx >> 2, cq = idx & 3;
      float4 v = make_float4(0.f, 0.f, 0.f, 0.f);
      if (nk < MS) v = *(const float4*)(sbase + (size_t)nk * CH + c0 + cq * 4);
      *(float4*)&stile[nk * 20 + cq * 4] = v;  // pad 20 => aligned b128, 2-way banks (free)
    }
    __syncthreads();
    #pragma unroll
    for (int cc = 0; cc < 16; cc += 4) {
      float a0[4], a1[4];
      #pragma unroll
      for (int u = 0; u < 4; ++u) {
        a0[u] = qld[(c0 + cc + u) * HW + ty];
        a1[u] = (ty < 9) ? qld[(c0 + cc + u) * HW + ty + 16] : 0.f;
      }
      #pragma unroll
      for (int j = 0; j < 8; ++j) {
        const float4 bv = *(const float4*)&stile[(tx + 16 * j) * 20 + cc];
        acc0[j] += a0[0] * bv.x + a0[1] * bv.y + a0[2] * bv.z + a0[3] * bv.w;
        acc1[j] += a1[0] * bv.x + a1[1] * bv.y + a1[2] * bv.z + a1[3] * bv.w;
      }
    }
  }
  __syncthreads();
  {
    float iv0 = invq[ty];
    float iv1 = (ty < 9) ? invq[ty + 16] : 0.f;
    #pragma unroll
    for (int j = 0; j < 8; ++j) {
      int col = tx + 16 * j;
      if (col < MS) {
        Sld[ty * MS + col] = acc0[j] * iv0;
        if (ty < 9) Sld[(ty + 16) * MS + col] = acc1[j] * iv1;
      }
    }
  }
  __syncthreads();

  float* P  = smem;         // 25 x 125 : T_sq rows
  float* Qm = smem + 3200;  // 125 x 25 : T_qs rows (column softmax of S)

  // row softmax with GAMMA -> P  (8 threads per row)
  {
    int i = tid >> 3, s8 = tid & 7;
    if (i < HW) {
      float mx = -1e30f;
      for (int j = s8; j < MS; j += 8) mx = fmaxf(mx, Sld[i * MS + j]);
      mx = fmaxf(mx, __shfl_xor(mx, 1));
      mx = fmaxf(mx, __shfl_xor(mx, 2));
      mx = fmaxf(mx, __shfl_xor(mx, 4));
      float sum = 0.f;
      for (int j = s8; j < MS; j += 8) {
        float e = __expf(GAMMA * (Sld[i * MS + j] - mx));
        P[i * MS + j] = e; sum += e;
      }
      sum += __shfl_xor(sum, 1); sum += __shfl_xor(sum, 2); sum += __shfl_xor(sum, 4);
      float is = 1.f / sum;
      for (int j = s8; j < MS; j += 8) P[i * MS + j] *= is;
    }
  }
  // column softmax with GAMMA2 -> Qm[j][i]  (one thread per column)
  if (tid < MS) {
    float mx = -1e30f;
    #pragma unroll
    for (int i = 0; i < HW; ++i) mx = fmaxf(mx, Sld[i * MS + tid]);
    float e[HW]; float sum = 0.f;
    #pragma unroll
    for (int i = 0; i < HW; ++i) { e[i] = __expf(GAMMA2 * (Sld[i * MS + tid] - mx)); sum += e[i]; }
    float is = 1.f / sum;
    #pragma unroll
    for (int i = 0; i < HW; ++i) Qm[tid * HW + i] = e[i] * is;
  }
  __syncthreads();

  // Build reduced system: (I - c^2 * B*A) x = 1 + c * B*1
  // (BA)[i][i'] = sum_j Qm[j][i] * P[i'][j];  (B*1)[i] = sum_j Qm[j][i]
  double* Msol = (double*)(smem + 6400);   // 25 x 26 (augmented), f64
  if (tid < HW) {
    float s = 0.f;
    for (int j = 0; j < MS; ++j) s += Qm[j * HW + tid];
    Msol[tid * 26 + 25] = 1.0 + KATZ * (double)s;
  }
  for (int e2 = tid; e2 < HW * HW; e2 += 256) {
    int i = e2 / HW, i2 = e2 - i * HW;
    float a = 0.f;
    for (int j = 0; j < MS; ++j) a += Qm[j * HW + i] * P[i2 * MS + j];
    double v = -(KATZ * KATZ) * (double)a;
    if (i == i2) v += 1.0;
    Msol[i * 26 + i2] = v;
  }
  __syncthreads();

  // Gaussian elimination, no pivoting (matrix is column-diagonally-dominant)
  for (int k = 0; k < HW - 1; ++k) {
    double invp = 1.0 / Msol[k * 26 + k];
    int jj = k + 1 + (tid & 31);
    for (int i = k + 1 + (tid >> 5); i < HW; i += 8) {
      double f = Msol[i * 26 + k] * invp;
      if (jj <= HW) Msol[i * 26 + jj] -= f * Msol[k * 26 + jj];
    }
    __syncthreads();
  }
  // back substitution (parallel backward elimination)
  double* xs = (double*)(smem + 8000);     // 25 f64
  for (int k = HW - 1; k >= 0; --k) {
    double xk = Msol[k * 26 + 25] / Msol[k * 26 + k];
    if (tid == 0) xs[k] = xk;
    if (tid < k) Msol[tid * 26 + 25] -= Msol[tid * 26 + k] * xk;
    __syncthreads();
  }

  // outputs: kq = x_q - 1 (normalized); ks = c * P^T x_q (per-n normalized)
  if (tid < HW) kqs[tid] = (float)(xs[tid] - 1.0);
  float* ksf = smem + 8100;                // 125
  if (tid < MS) {
    float a = 0.f;
    #pragma unroll
    for (int i = 0; i < HW; ++i) a += P[i * MS + tid] * (float)xs[i];
    ksf[tid] = (float)KATZ * a;
  }
  __syncthreads();
  if (tid < HW) {
    float s = 0.f;
    #pragma unroll
    for (int i = 0; i < HW; ++i) s += kqs[i];
    out[(size_t)bq * HW + tid] = kqs[tid] / s;
  }
  if (tid < MS) {
    int n = tid / HW;
    float s = 0.f;
    #pragma unroll
    for (int k2 = 0; k2 < HW; ++k2) s += ksf[n * HW + k2];
    out[(size_t)(BATCH * NQ * HW) + (size_t)bq * MS + tid] = ksf[tid] / s;
  }
}

extern "C" void kernel_launch(void* const* d_in, const int* in_sizes, int n_in,
                              void* d_out, int out_size, void* d_ws, size_t ws_size,
                              hipStream_t stream) {
  const float* sup = (const float*)d_in[0];
  const float* qry = (const float*)d_in[1];
  float* outp = (float*)d_out;
  float* sup_t = (float*)d_ws;             // 32*125*640 f32 = 10.24 MB
  prep_sup_kernel<<<BATCH * NWAY, 256, 0, stream>>>(sup, sup_t);
  melmask_kernel<<<BATCH * NQ, 256, 0, stream>>>(qry, sup_t, outp);
}